// Round 5
// baseline (321.114 us; speedup 1.0000x reference)
//
#include <hip/hip_runtime.h>

#define NN 50000
#define EE 800000
#define DIM 128
#define KK 256          // concat K: [agg(128) | self(128)]
#define OUTD 4
#define EPSV 1e-5f
#define OTS 132         // oT row stride (floats)

using short8v = __attribute__((ext_vector_type(8))) short;   // 8 bf16
using f32x4v  = __attribute__((ext_vector_type(4))) float;

__device__ __forceinline__ unsigned short f2bf(float f) {
    union { float f; unsigned u; } x; x.f = f;
    unsigned r = x.u + 0x7FFF + ((x.u >> 16) & 1);   // RNE
    return (unsigned short)(r >> 16);
}
__device__ __forceinline__ float bf2f(unsigned short u) {
    union { unsigned u; float f; } x; x.u = ((unsigned)u) << 16;
    return x.f;
}

// ---------------------------------------------------------------------------
// prep: role-split grid.
//   blocks [0, 6250):        x f32 -> xb bf16 (1 float4/thread, exact)
//   blocks [6250, 6506):     Wt bf16 [128 j][256 k] for both layers
//   blocks [6506, 9631):     dst histogram (cnt must be pre-zeroed)
// ---------------------------------------------------------------------------
#define XB_BLK 6250
#define W_BLK  256
#define H_BLK  3125
__global__ __launch_bounds__(256) void prep_kernel(
    const float* __restrict__ x, ushort* __restrict__ xb,
    const float* __restrict__ Wl0, const float* __restrict__ Wr0,
    const float* __restrict__ Wl1, const float* __restrict__ Wr1,
    ushort* __restrict__ Wt0, ushort* __restrict__ Wt1,
    const int* __restrict__ dst, int* __restrict__ cnt)
{
    int b = blockIdx.x;
    if (b < XB_BLK) {
        int i = b * 256 + threadIdx.x;             // < 1,600,000 exactly
        float4 v = ((const float4*)x)[i];
        ushort4 o;
        o.x = f2bf(v.x); o.y = f2bf(v.y); o.z = f2bf(v.z); o.w = f2bf(v.w);
        ((ushort4*)xb)[i] = o;
    } else if (b < XB_BLK + W_BLK) {
        int idx = (b - XB_BLK) * 256 + threadIdx.x;   // 0..65535
        int which = idx >> 15;
        int j = (idx >> 8) & 127;
        int k = idx & 255;
        const float* Wl = which ? Wl1 : Wl0;
        const float* Wr = which ? Wr1 : Wr0;
        ushort* Wt = which ? Wt1 : Wt0;
        float v = (k < 128) ? Wl[k * DIM + j] : Wr[(k - 128) * DIM + j];
        Wt[j * KK + k] = f2bf(v);
    } else {
        int e = (b - XB_BLK - W_BLK) * 256 + threadIdx.x;
        if (e < EE) atomicAdd(&cnt[dst[e]], 1);
    }
}

// ---------------------------------------------------------------------------
// Register-blocked exclusive scan, one block of 1024 threads.
// Thread t owns ints [t*52, t*52+52) (13 int4). One block-scan round.
// Writes rowptr[0..NN] and cursor[0..NN) = rowptr (fill bumps cursor).
// ---------------------------------------------------------------------------
__global__ __launch_bounds__(1024) void scan_kernel(
    const int* __restrict__ cnt, int* __restrict__ rowptr,
    int* __restrict__ cursor)
{
    __shared__ int wsum[16];
    int tid = threadIdx.x, lane = tid & 63, wid = tid >> 6;
    int4 q[13];
    #pragma unroll
    for (int j = 0; j < 13; j++) {
        int qi = tid * 13 + j;
        int4 v = make_int4(0, 0, 0, 0);
        if (qi < NN / 4) v = ((const int4*)cnt)[qi];
        q[j] = v;
    }
    // in-place: q[j] components -> local exclusive prefix; run = thread total
    int run = 0;
    #pragma unroll
    for (int j = 0; j < 13; j++) {
        int a;
        a = q[j].x; q[j].x = run; run += a;
        a = q[j].y; q[j].y = run; run += a;
        a = q[j].z; q[j].z = run; run += a;
        a = q[j].w; q[j].w = run; run += a;
    }
    int tot = run;
    int s = tot;
    #pragma unroll
    for (int off = 1; off < 64; off <<= 1) {
        int u = __shfl_up(s, off, 64);
        if (lane >= off) s += u;
    }
    if (lane == 63) wsum[wid] = s;
    __syncthreads();
    if (tid < 16) {
        int wv = wsum[tid];
        #pragma unroll
        for (int off = 1; off < 16; off <<= 1) {
            int u = __shfl_up(wv, off, 16);
            if (tid >= off) wv += u;
        }
        wsum[tid] = wv;
    }
    __syncthreads();
    int excl = (wid ? wsum[wid - 1] : 0) + (s - tot);

    #pragma unroll
    for (int j = 0; j < 13; j++) {
        int qi = tid * 13 + j;
        int bi = qi * 4;
        int4 o = make_int4(q[j].x + excl, q[j].y + excl, q[j].z + excl, q[j].w + excl);
        if (bi + 3 < NN) {
            ((int4*)rowptr)[qi] = o;
            ((int4*)cursor)[qi] = o;
        } else if (bi <= NN) {
            int vv[4] = { o.x, o.y, o.z, o.w };
            #pragma unroll
            for (int c = 0; c < 4; c++) {
                int idx = bi + c;
                if (idx < NN) { rowptr[idx] = vv[c]; cursor[idx] = vv[c]; }
                else if (idx == NN) rowptr[idx] = vv[c];
            }
        }
    }
}

// ---------------------------------------------------------------------------
// fill: cursor pre-initialized to rowptr -> atomicAdd returns absolute slot.
// ---------------------------------------------------------------------------
__global__ __launch_bounds__(256) void fill_kernel(
    const int* __restrict__ src, const int* __restrict__ dst,
    int* __restrict__ cursor, int* __restrict__ col)
{
    int e = blockIdx.x * 256 + threadIdx.x;
    if (e >= EE) return;
    int pos = atomicAdd(&cursor[dst[e]], 1);
    col[pos] = src[e];
}

// ---------------------------------------------------------------------------
// Fused layer (bf16 features, MFMA GEMM). Gather: per node, each half-wave
// (32 lanes x ushort4 = 256B row) takes one edge parity with 4-deep
// predicated unroll => 8 rows in flight per wave.
// ---------------------------------------------------------------------------
template <int DO_HEAD>
__global__ __launch_bounds__(256) void sage_fused_kernel(
    const ushort* __restrict__ featG,     // bf16 [N][128]
    const int* __restrict__ rowptr, const int* __restrict__ col,
    const ushort* __restrict__ WtB,       // bf16 [128 j][256 k]
    const float* __restrict__ bl,
    const float* __restrict__ g, const float* __restrict__ beta,
    const float* __restrict__ Wh, const float* __restrict__ bh,
    void* __restrict__ outp)
{
    __shared__ __align__(16) char smem[32 * OTS * 4];   // 16.9 KB
    __shared__ float mu_s[32], ri_s[32];
    ushort* featB = (ushort*)smem;            // [32][256] bf16, swizzled
    float*  oT    = (float*)smem;             // overlays featB after MFMA
    #define OT(n, k) oT[(n) * OTS + (k)]

    int tid = threadIdx.x;
    int base = blockIdx.x * 32;
    int lane = tid & 63, w = tid >> 6;

    // ---- self-feature part: featB[n][128..256) ----
    #pragma unroll
    for (int i = 0; i < 4; i++) {
        int idx = tid + i * 256;
        int n = idx >> 5, c = idx & 31;
        int node = base + n;
        ushort4 xv = make_ushort4(0, 0, 0, 0);
        if (node < NN) xv = *(const ushort4*)(featG + (size_t)node * DIM + c * 4);
        int kb = (256 + c * 8) ^ ((n & 7) << 4);
        *(ushort4*)(featB + n * KK + (kb >> 1)) = xv;
    }

    // ---- gather-mean: featB[n][0..128) ----
    {
        int half = lane >> 5, l32 = lane & 31;
        for (int i = 0; i < 8; i++) {
            int n = w * 8 + i;
            int node = base + n;
            int beg = 0, end = 0;
            if (node < NN) { beg = rowptr[node]; end = rowptr[node + 1]; }
            int deg = end - beg;
            float a0x=0.f,a0y=0.f,a0z=0.f,a0w=0.f;
            float a1x=0.f,a1y=0.f,a1z=0.f,a1w=0.f;
            float a2x=0.f,a2y=0.f,a2z=0.f,a2w=0.f;
            float a3x=0.f,a3y=0.f,a3z=0.f,a3w=0.f;
            for (int e = beg + half; e < end; e += 8) {
                int lim = end - 1;
                int e1 = e + 2, e2 = e + 4, e3 = e + 6;
                int s0 = col[e];
                int s1 = col[min(e1, lim)];
                int s2 = col[min(e2, lim)];
                int s3 = col[min(e3, lim)];
                ushort4 v0 = *(const ushort4*)(featG + (size_t)s0 * DIM + l32 * 4);
                ushort4 v1 = *(const ushort4*)(featG + (size_t)s1 * DIM + l32 * 4);
                ushort4 v2 = *(const ushort4*)(featG + (size_t)s2 * DIM + l32 * 4);
                ushort4 v3 = *(const ushort4*)(featG + (size_t)s3 * DIM + l32 * 4);
                float m1 = (e1 < end) ? 1.f : 0.f;
                float m2 = (e2 < end) ? 1.f : 0.f;
                float m3 = (e3 < end) ? 1.f : 0.f;
                a0x += bf2f(v0.x); a0y += bf2f(v0.y); a0z += bf2f(v0.z); a0w += bf2f(v0.w);
                a1x = fmaf(m1, bf2f(v1.x), a1x); a1y = fmaf(m1, bf2f(v1.y), a1y);
                a1z = fmaf(m1, bf2f(v1.z), a1z); a1w = fmaf(m1, bf2f(v1.w), a1w);
                a2x = fmaf(m2, bf2f(v2.x), a2x); a2y = fmaf(m2, bf2f(v2.y), a2y);
                a2z = fmaf(m2, bf2f(v2.z), a2z); a2w = fmaf(m2, bf2f(v2.w), a2w);
                a3x = fmaf(m3, bf2f(v3.x), a3x); a3y = fmaf(m3, bf2f(v3.y), a3y);
                a3z = fmaf(m3, bf2f(v3.z), a3z); a3w = fmaf(m3, bf2f(v3.w), a3w);
            }
            a0x += a1x + a2x + a3x;
            a0y += a1y + a2y + a3y;
            a0z += a1z + a2z + a3z;
            a0w += a1w + a2w + a3w;
            a0x += __shfl_xor(a0x, 32, 64);
            a0y += __shfl_xor(a0y, 32, 64);
            a0z += __shfl_xor(a0z, 32, 64);
            a0w += __shfl_xor(a0w, 32, 64);
            if (half == 0) {
                float di = 1.0f / fmaxf((float)deg, 1.0f);
                ushort4 o;
                o.x = f2bf(a0x * di); o.y = f2bf(a0y * di);
                o.z = f2bf(a0z * di); o.w = f2bf(a0w * di);
                int kb = (l32 * 8) ^ ((n & 7) << 4);
                *(ushort4*)(featB + n * KK + (kb >> 1)) = o;
            }
        }
    }
    __syncthreads();

    // ---- MFMA: C[32][128] = featB[32][256] x W[256][128] ----
    int l15 = lane & 15, q = lane >> 4;
    f32x4v acc00 = {}, acc01 = {}, acc10 = {}, acc11 = {};
    const ushort* wbase = WtB + (size_t)(w * 32) * KK;
    int n0 = l15, n1 = 16 + l15;
    int sw = (l15 & 7) << 4;
    #pragma unroll
    for (int ks = 0; ks < 8; ks++) {
        int kbA = ks * 64 + q * 16;
        short8v a0 = *(const short8v*)(featB + n0 * KK + (((kbA) ^ sw) >> 1));
        short8v a1 = *(const short8v*)(featB + n1 * KK + (((kbA) ^ sw) >> 1));
        int koff = ks * 32 + q * 8;
        short8v b0 = *(const short8v*)(wbase + (size_t)l15 * KK + koff);
        short8v b1 = *(const short8v*)(wbase + (size_t)(16 + l15) * KK + koff);
        acc00 = __builtin_amdgcn_mfma_f32_16x16x32_bf16(a0, b0, acc00, 0, 0, 0);
        acc01 = __builtin_amdgcn_mfma_f32_16x16x32_bf16(a0, b1, acc01, 0, 0, 0);
        acc10 = __builtin_amdgcn_mfma_f32_16x16x32_bf16(a1, b0, acc10, 0, 0, 0);
        acc11 = __builtin_amdgcn_mfma_f32_16x16x32_bf16(a1, b1, acc11, 0, 0, 0);
    }
    __syncthreads();   // all featB reads done before oT overlays it

    // D layout: col = lane&15, row = (lane>>4)*4 + r
    {
        int c0 = w * 32 + l15, c1 = c0 + 16;
        float bl0v = bl[c0], bl1v = bl[c1];
        #pragma unroll
        for (int r = 0; r < 4; r++) {
            int r0 = q * 4 + r, r1 = 16 + q * 4 + r;
            OT(r0, c0) = acc00[r] + bl0v;
            OT(r0, c1) = acc01[r] + bl1v;
            OT(r1, c0) = acc10[r] + bl0v;
            OT(r1, c1) = acc11[r] + bl1v;
        }
    }
    __syncthreads();

    // ---- LayerNorm stats (f32): 8 threads per node ----
    {
        int n = tid >> 3, l = tid & 7;
        float s = 0.f, s2 = 0.f;
        #pragma unroll
        for (int kk = 0; kk < 16; kk++) {
            float v = OT(n, l * 16 + kk);
            s += v; s2 += v * v;
        }
        #pragma unroll
        for (int off = 4; off; off >>= 1) {
            s  += __shfl_down(s, off, 8);
            s2 += __shfl_down(s2, off, 8);
        }
        if (l == 0) {
            float mu = s * (1.0f / DIM);
            float var = s2 * (1.0f / DIM) - mu * mu;
            mu_s[n] = mu;
            ri_s[n] = rsqrtf(fmaxf(var, 0.f) + EPSV);
        }
    }
    __syncthreads();

    if (!DO_HEAD) {
        ushort* hout = (ushort*)outp;
        #pragma unroll
        for (int i = 0; i < 16; i++) {
            int idx = tid + i * 256;
            int n = idx >> 7, k = idx & 127;
            int node = base + n;
            if (node < NN) {
                float v = (OT(n, k) - mu_s[n]) * ri_s[n] * g[k] + beta[k];
                hout[(size_t)node * DIM + k] = f2bf(fmaxf(v, 0.f));
            }
        }
    } else {
        float* fout = (float*)outp;
        float vals[16];
        #pragma unroll
        for (int i = 0; i < 16; i++) {
            int idx = tid + i * 256;
            int n = idx >> 7, k = idx & 127;
            float v = (OT(n, k) - mu_s[n]) * ri_s[n] * g[k] + beta[k];
            vals[i] = fmaxf(v, 0.f);
        }
        __syncthreads();
        #pragma unroll
        for (int i = 0; i < 16; i++) {
            int idx = tid + i * 256;
            int n = idx >> 7, k = idx & 127;
            OT(n, k) = vals[i];
        }
        __syncthreads();
        if (tid < 128) {
            int n = tid >> 2, o = tid & 3;
            int node = base + n;
            if (node < NN) {
                float s = bh[o];
                for (int k = 0; k < DIM; k++) s += OT(n, k) * Wh[k * OUTD + o];
                fout[(size_t)node * OUTD + o] = s;
            }
        }
    }
    #undef OT
}

extern "C" void kernel_launch(void* const* d_in, const int* in_sizes, int n_in,
                              void* d_out, int out_size, void* d_ws, size_t ws_size,
                              hipStream_t stream)
{
    const float* x    = (const float*)d_in[0];
    const int*   ei   = (const int*)d_in[1];   // [2, E] int32
    const float* Wl0  = (const float*)d_in[2];
    const float* bl0  = (const float*)d_in[3];
    const float* Wr0  = (const float*)d_in[4];
    const float* Wl1  = (const float*)d_in[5];
    const float* bl1  = (const float*)d_in[6];
    const float* Wr1  = (const float*)d_in[7];
    const float* g0   = (const float*)d_in[8];
    const float* be0  = (const float*)d_in[9];
    const float* g1   = (const float*)d_in[10];
    const float* be1  = (const float*)d_in[11];
    const float* Wh   = (const float*)d_in[12];
    const float* bh   = (const float*)d_in[13];
    float* out = (float*)d_out;

    const int* srcI = ei;
    const int* dstI = ei + EE;

    // ws layout (16B-aligned): xb | h | Wt0 | Wt1 | rowptr | cnt | cursor | col
    char* p = (char*)d_ws;
    ushort* xb     = (ushort*)p;  p += (size_t)NN * DIM * 2;   // 12.8 MB
    ushort* h      = (ushort*)p;  p += (size_t)NN * DIM * 2;   // 12.8 MB
    ushort* Wt0    = (ushort*)p;  p += DIM * KK * 2;           // 64 KB
    ushort* Wt1    = (ushort*)p;  p += DIM * KK * 2;           // 64 KB
    int*    rowptr = (int*)p;     p += 50016 * 4;              // N+1, padded
    int*    cnt    = (int*)p;     p += NN * 4;
    int*    cursor = (int*)p;     p += NN * 4;
    int*    col    = (int*)p;

    hipMemsetAsync(cnt, 0, NN * sizeof(int), stream);
    prep_kernel<<<XB_BLK + W_BLK + H_BLK, 256, 0, stream>>>(
        x, xb, Wl0, Wr0, Wl1, Wr1, Wt0, Wt1, dstI, cnt);
    scan_kernel<<<1, 1024, 0, stream>>>(cnt, rowptr, cursor);
    fill_kernel<<<(EE + 255) / 256, 256, 0, stream>>>(srcI, dstI, cursor, col);

    const int blocks = (NN + 31) / 32;
    sage_fused_kernel<0><<<blocks, 256, 0, stream>>>(
        xb, rowptr, col, Wt0, bl0, g0, be0, nullptr, nullptr, (void*)h);
    sage_fused_kernel<1><<<blocks, 256, 0, stream>>>(
        h, rowptr, col, Wt1, bl1, g1, be1, Wh, bh, (void*)out);
}

// Round 6
// 295.238 us; speedup vs baseline: 1.0876x; 1.0876x over previous
//
#include <hip/hip_runtime.h>

#define NN 50000
#define EE 800000
#define DIM 128
#define KK 256          // concat K: [agg(128) | self(128)]
#define OUTD 4
#define EPSV 1e-5f
#define OTS 132         // oT row stride (floats)

using short8v = __attribute__((ext_vector_type(8))) short;   // 8 bf16
using f32x4v  = __attribute__((ext_vector_type(4))) float;

__device__ __forceinline__ unsigned short f2bf(float f) {
    union { float f; unsigned u; } x; x.f = f;
    unsigned r = x.u + 0x7FFF + ((x.u >> 16) & 1);   // RNE
    return (unsigned short)(r >> 16);
}
__device__ __forceinline__ float bf2f(unsigned short u) {
    union { unsigned u; float f; } x; x.u = ((unsigned)u) << 16;
    return x.f;
}

// ---------------------------------------------------------------------------
// prep: role-split grid.
//   blocks [0, 6250):        x f32 -> xb bf16 (1 float4/thread, exact)
//   blocks [6250, 6506):     Wt bf16 [128 j][256 k] for both layers
//   blocks [6506, 9631):     dst histogram (cnt pre-zeroed by memset)
// ---------------------------------------------------------------------------
#define XB_BLK 6250
#define W_BLK  256
#define H_BLK  3125
__global__ __launch_bounds__(256) void prep_kernel(
    const float* __restrict__ x, ushort* __restrict__ xb,
    const float* __restrict__ Wl0, const float* __restrict__ Wr0,
    const float* __restrict__ Wl1, const float* __restrict__ Wr1,
    ushort* __restrict__ Wt0, ushort* __restrict__ Wt1,
    const int* __restrict__ dst, int* __restrict__ cnt)
{
    int b = blockIdx.x;
    if (b < XB_BLK) {
        int i = b * 256 + threadIdx.x;             // < 1,600,000 exactly
        float4 v = ((const float4*)x)[i];
        ushort4 o;
        o.x = f2bf(v.x); o.y = f2bf(v.y); o.z = f2bf(v.z); o.w = f2bf(v.w);
        ((ushort4*)xb)[i] = o;
    } else if (b < XB_BLK + W_BLK) {
        int idx = (b - XB_BLK) * 256 + threadIdx.x;   // 0..65535
        int which = idx >> 15;
        int j = (idx >> 8) & 127;
        int k = idx & 255;
        const float* Wl = which ? Wl1 : Wl0;
        const float* Wr = which ? Wr1 : Wr0;
        ushort* Wt = which ? Wt1 : Wt0;
        float v = (k < 128) ? Wl[k * DIM + j] : Wr[(k - 128) * DIM + j];
        Wt[j * KK + k] = f2bf(v);
    } else {
        int e = (b - XB_BLK - W_BLK) * 256 + threadIdx.x;
        if (e < EE) atomicAdd(&cnt[dst[e]], 1);
    }
}

// ---------------------------------------------------------------------------
// Register-blocked exclusive scan, one block of 1024 threads.
// Thread t owns ints [t*52, t*52+52) (13 int4). One block-scan round.
// Writes rowptr[0..NN] and cursor[0..NN) = rowptr (fill bumps cursor).
// ---------------------------------------------------------------------------
__global__ __launch_bounds__(1024) void scan_kernel(
    const int* __restrict__ cnt, int* __restrict__ rowptr,
    int* __restrict__ cursor)
{
    __shared__ int wsum[16];
    int tid = threadIdx.x, lane = tid & 63, wid = tid >> 6;
    int4 q[13];
    #pragma unroll
    for (int j = 0; j < 13; j++) {
        int qi = tid * 13 + j;
        int4 v = make_int4(0, 0, 0, 0);
        if (qi < NN / 4) v = ((const int4*)cnt)[qi];
        q[j] = v;
    }
    int run = 0;
    #pragma unroll
    for (int j = 0; j < 13; j++) {
        int a;
        a = q[j].x; q[j].x = run; run += a;
        a = q[j].y; q[j].y = run; run += a;
        a = q[j].z; q[j].z = run; run += a;
        a = q[j].w; q[j].w = run; run += a;
    }
    int tot = run;
    int s = tot;
    #pragma unroll
    for (int off = 1; off < 64; off <<= 1) {
        int u = __shfl_up(s, off, 64);
        if (lane >= off) s += u;
    }
    if (lane == 63) wsum[wid] = s;
    __syncthreads();
    if (tid < 16) {
        int wv = wsum[tid];
        #pragma unroll
        for (int off = 1; off < 16; off <<= 1) {
            int u = __shfl_up(wv, off, 16);
            if (tid >= off) wv += u;
        }
        wsum[tid] = wv;
    }
    __syncthreads();
    int excl = (wid ? wsum[wid - 1] : 0) + (s - tot);

    #pragma unroll
    for (int j = 0; j < 13; j++) {
        int qi = tid * 13 + j;
        int bi = qi * 4;
        int4 o = make_int4(q[j].x + excl, q[j].y + excl, q[j].z + excl, q[j].w + excl);
        if (bi + 3 < NN) {
            ((int4*)rowptr)[qi] = o;
            ((int4*)cursor)[qi] = o;
        } else if (bi <= NN) {
            int vv[4] = { o.x, o.y, o.z, o.w };
            #pragma unroll
            for (int c = 0; c < 4; c++) {
                int idx = bi + c;
                if (idx < NN) { rowptr[idx] = vv[c]; cursor[idx] = vv[c]; }
                else if (idx == NN) rowptr[idx] = vv[c];
            }
        }
    }
}

// ---------------------------------------------------------------------------
// fill: cursor pre-initialized to rowptr -> atomicAdd returns absolute slot.
// ---------------------------------------------------------------------------
__global__ __launch_bounds__(256) void fill_kernel(
    const int* __restrict__ src, const int* __restrict__ dst,
    int* __restrict__ cursor, int* __restrict__ col)
{
    int e = blockIdx.x * 256 + threadIdx.x;
    if (e >= EE) return;
    int pos = atomicAdd(&cursor[dst[e]], 1);
    col[pos] = src[e];
}

// ---------------------------------------------------------------------------
// Fused layer. Gather: wave = 4 groups of 16 lanes; each group owns edge
// parity (e % 4), ushort8 = 16B/lane covers a 256B row; 2-deep unroll
// => 8 rows in flight per wave. rowptr preloaded via lanes + shfl.
// ---------------------------------------------------------------------------
template <int DO_HEAD>
__global__ __launch_bounds__(256) void sage_fused_kernel(
    const ushort* __restrict__ featG,     // bf16 [N][128]
    const int* __restrict__ rowptr, const int* __restrict__ col,
    const ushort* __restrict__ WtB,       // bf16 [128 j][256 k]
    const float* __restrict__ bl,
    const float* __restrict__ g, const float* __restrict__ beta,
    const float* __restrict__ Wh, const float* __restrict__ bh,
    void* __restrict__ outp)
{
    __shared__ __align__(16) char smem[32 * OTS * 4];   // 16.9 KB
    __shared__ float mu_s[32], ri_s[32];
    ushort* featB = (ushort*)smem;            // [32][256] bf16, swizzled
    float*  oT    = (float*)smem;             // overlays featB after MFMA
    #define OT(n, k) oT[(n) * OTS + (k)]

    int tid = threadIdx.x;
    int base = blockIdx.x * 32;
    int lane = tid & 63, w = tid >> 6;

    // ---- self-feature part: featB[n][128..256), ushort8 ----
    #pragma unroll
    for (int i = 0; i < 2; i++) {
        int idx = tid + i * 256;
        int n = idx >> 4, c = idx & 15;
        int node = base + n;
        short8v xv = {};
        if (node < NN) xv = *(const short8v*)(featG + (size_t)node * DIM + c * 8);
        int kb = (256 + c * 16) ^ ((n & 7) << 4);
        *(short8v*)(featB + n * KK + (kb >> 1)) = xv;
    }

    // ---- gather-mean: featB[n][0..128) ----
    {
        int lane16 = lane & 15, grp = lane >> 4;
        // Preload this wave's 9 rowptr entries (nodes w*8 .. w*8+8).
        int rp = 0;
        {
            int ridx = base + w * 8 + lane;
            if (lane < 9) rp = rowptr[min(ridx, NN)];
        }
        for (int i = 0; i < 8; i++) {
            int n = w * 8 + i;
            int beg = __shfl(rp, i, 64);
            int end = __shfl(rp, i + 1, 64);
            int deg = end - beg;
            float a0[8], a1[8];
            #pragma unroll
            for (int c = 0; c < 8; c++) { a0[c] = 0.f; a1[c] = 0.f; }
            int e = beg + grp;
            for (; e + 4 < end; e += 8) {
                int s0 = col[e], s1 = col[e + 4];
                short8v v0 = *(const short8v*)(featG + (size_t)s0 * DIM + lane16 * 8);
                short8v v1 = *(const short8v*)(featG + (size_t)s1 * DIM + lane16 * 8);
                #pragma unroll
                for (int c = 0; c < 8; c++) {
                    a0[c] += bf2f((unsigned short)v0[c]);
                    a1[c] += bf2f((unsigned short)v1[c]);
                }
            }
            if (e < end) {
                int s0 = col[e];
                short8v v0 = *(const short8v*)(featG + (size_t)s0 * DIM + lane16 * 8);
                #pragma unroll
                for (int c = 0; c < 8; c++) a0[c] += bf2f((unsigned short)v0[c]);
            }
            #pragma unroll
            for (int c = 0; c < 8; c++) {
                a0[c] += a1[c];
                a0[c] += __shfl_xor(a0[c], 16, 64);
                a0[c] += __shfl_xor(a0[c], 32, 64);
            }
            if (grp == 0) {
                float di = 1.0f / fmaxf((float)deg, 1.0f);
                short8v o;
                #pragma unroll
                for (int c = 0; c < 8; c++) o[c] = (short)f2bf(a0[c] * di);
                int kb = (lane16 * 16) ^ ((n & 7) << 4);
                *(short8v*)(featB + n * KK + (kb >> 1)) = o;
            }
        }
    }
    __syncthreads();

    // ---- MFMA: C[32][128] = featB[32][256] x W[256][128] ----
    int l15 = lane & 15, q = lane >> 4;
    f32x4v acc00 = {}, acc01 = {}, acc10 = {}, acc11 = {};
    const ushort* wbase = WtB + (size_t)(w * 32) * KK;
    int n0 = l15, n1 = 16 + l15;
    int sw = (l15 & 7) << 4;
    #pragma unroll
    for (int ks = 0; ks < 8; ks++) {
        int kbA = ks * 64 + q * 16;
        short8v a0 = *(const short8v*)(featB + n0 * KK + (((kbA) ^ sw) >> 1));
        short8v a1 = *(const short8v*)(featB + n1 * KK + (((kbA) ^ sw) >> 1));
        int koff = ks * 32 + q * 8;
        short8v b0 = *(const short8v*)(wbase + (size_t)l15 * KK + koff);
        short8v b1 = *(const short8v*)(wbase + (size_t)(16 + l15) * KK + koff);
        acc00 = __builtin_amdgcn_mfma_f32_16x16x32_bf16(a0, b0, acc00, 0, 0, 0);
        acc01 = __builtin_amdgcn_mfma_f32_16x16x32_bf16(a0, b1, acc01, 0, 0, 0);
        acc10 = __builtin_amdgcn_mfma_f32_16x16x32_bf16(a1, b0, acc10, 0, 0, 0);
        acc11 = __builtin_amdgcn_mfma_f32_16x16x32_bf16(a1, b1, acc11, 0, 0, 0);
    }
    __syncthreads();   // all featB reads done before oT overlays it

    // D layout: col = lane&15, row = (lane>>4)*4 + r
    {
        int c0 = w * 32 + l15, c1 = c0 + 16;
        float bl0v = bl[c0], bl1v = bl[c1];
        #pragma unroll
        for (int r = 0; r < 4; r++) {
            int r0 = q * 4 + r, r1 = 16 + q * 4 + r;
            OT(r0, c0) = acc00[r] + bl0v;
            OT(r0, c1) = acc01[r] + bl1v;
            OT(r1, c0) = acc10[r] + bl0v;
            OT(r1, c1) = acc11[r] + bl1v;
        }
    }
    __syncthreads();

    // ---- LayerNorm stats (f32): 8 threads per node ----
    {
        int n = tid >> 3, l = tid & 7;
        float s = 0.f, s2 = 0.f;
        #pragma unroll
        for (int kk = 0; kk < 16; kk++) {
            float v = OT(n, l * 16 + kk);
            s += v; s2 += v * v;
        }
        #pragma unroll
        for (int off = 4; off; off >>= 1) {
            s  += __shfl_down(s, off, 8);
            s2 += __shfl_down(s2, off, 8);
        }
        if (l == 0) {
            float mu = s * (1.0f / DIM);
            float var = s2 * (1.0f / DIM) - mu * mu;
            mu_s[n] = mu;
            ri_s[n] = rsqrtf(fmaxf(var, 0.f) + EPSV);
        }
    }
    __syncthreads();

    if (!DO_HEAD) {
        ushort* hout = (ushort*)outp;
        #pragma unroll
        for (int i = 0; i < 16; i++) {
            int idx = tid + i * 256;
            int n = idx >> 7, k = idx & 127;
            int node = base + n;
            if (node < NN) {
                float v = (OT(n, k) - mu_s[n]) * ri_s[n] * g[k] + beta[k];
                hout[(size_t)node * DIM + k] = f2bf(fmaxf(v, 0.f));
            }
        }
    } else {
        float* fout = (float*)outp;
        float vals[16];
        #pragma unroll
        for (int i = 0; i < 16; i++) {
            int idx = tid + i * 256;
            int n = idx >> 7, k = idx & 127;
            float v = (OT(n, k) - mu_s[n]) * ri_s[n] * g[k] + beta[k];
            vals[i] = fmaxf(v, 0.f);
        }
        __syncthreads();
        #pragma unroll
        for (int i = 0; i < 16; i++) {
            int idx = tid + i * 256;
            int n = idx >> 7, k = idx & 127;
            OT(n, k) = vals[i];
        }
        __syncthreads();
        if (tid < 128) {
            int n = tid >> 2, o = tid & 3;
            int node = base + n;
            if (node < NN) {
                float s = bh[o];
                for (int k = 0; k < DIM; k++) s += OT(n, k) * Wh[k * OUTD + o];
                fout[(size_t)node * OUTD + o] = s;
            }
        }
    }
    #undef OT
}

extern "C" void kernel_launch(void* const* d_in, const int* in_sizes, int n_in,
                              void* d_out, int out_size, void* d_ws, size_t ws_size,
                              hipStream_t stream)
{
    const float* x    = (const float*)d_in[0];
    const int*   ei   = (const int*)d_in[1];   // [2, E] int32
    const float* Wl0  = (const float*)d_in[2];
    const float* bl0  = (const float*)d_in[3];
    const float* Wr0  = (const float*)d_in[4];
    const float* Wl1  = (const float*)d_in[5];
    const float* bl1  = (const float*)d_in[6];
    const float* Wr1  = (const float*)d_in[7];
    const float* g0   = (const float*)d_in[8];
    const float* be0  = (const float*)d_in[9];
    const float* g1   = (const float*)d_in[10];
    const float* be1  = (const float*)d_in[11];
    const float* Wh   = (const float*)d_in[12];
    const float* bh   = (const float*)d_in[13];
    float* out = (float*)d_out;

    const int* srcI = ei;
    const int* dstI = ei + EE;

    // ws layout (16B-aligned): xb | h | Wt0 | Wt1 | rowptr | cnt | cursor | col
    char* p = (char*)d_ws;
    ushort* xb     = (ushort*)p;  p += (size_t)NN * DIM * 2;   // 12.8 MB
    ushort* h      = (ushort*)p;  p += (size_t)NN * DIM * 2;   // 12.8 MB
    ushort* Wt0    = (ushort*)p;  p += DIM * KK * 2;           // 64 KB
    ushort* Wt1    = (ushort*)p;  p += DIM * KK * 2;           // 64 KB
    int*    rowptr = (int*)p;     p += 50016 * 4;              // N+1, padded
    int*    cnt    = (int*)p;     p += NN * 4;
    int*    cursor = (int*)p;     p += NN * 4;
    int*    col    = (int*)p;

    hipMemsetAsync(cnt, 0, NN * sizeof(int), stream);
    prep_kernel<<<XB_BLK + W_BLK + H_BLK, 256, 0, stream>>>(
        x, xb, Wl0, Wr0, Wl1, Wr1, Wt0, Wt1, dstI, cnt);
    scan_kernel<<<1, 1024, 0, stream>>>(cnt, rowptr, cursor);
    fill_kernel<<<(EE + 255) / 256, 256, 0, stream>>>(srcI, dstI, cursor, col);

    const int blocks = (NN + 31) / 32;
    sage_fused_kernel<0><<<blocks, 256, 0, stream>>>(
        xb, rowptr, col, Wt0, bl0, g0, be0, nullptr, nullptr, (void*)h);
    sage_fused_kernel<1><<<blocks, 256, 0, stream>>>(
        h, rowptr, col, Wt1, bl1, g1, be1, Wh, bh, (void*)out);
}